// Round 4
// baseline (236.188 us; speedup 1.0000x reference)
//
#include <hip/hip_runtime.h>
#include <stdint.h>

#define BDIM 4
#define CDIM 512
#define HDIM 128
#define WDIM 128
#define HWDIM (HDIM*WDIM)
#define SADMP 16
#define BHW 8
#define KKP 256

using short8 = __attribute__((ext_vector_type(8))) short;
using f32x4  = __attribute__((ext_vector_type(4))) float;

__device__ __forceinline__ unsigned short f2bf(float f) {
    unsigned u = __float_as_uint(f);
    unsigned r = (u + 0x7fffu + ((u >> 16) & 1u)) >> 16;
    return (unsigned short)r;
}
__device__ __forceinline__ float bf2f(unsigned short h) {
    return __uint_as_float(((unsigned)h) << 16);
}
__device__ __forceinline__ unsigned int ordf(float f) {
    unsigned u = __float_as_uint(f);
    return (u & 0x80000000u) ? ~u : (u | 0x80000000u);
}

// ---------------- K1: resp[b][hw] = sum_c A[b][c][hw] ----------------
__global__ void resp_kernel(const float* __restrict__ A, float* __restrict__ resp) {
    int gid = blockIdx.x * blockDim.x + threadIdx.x;
    int b = gid / HWDIM, hw = gid % HWDIM;
    const float* p = A + (size_t)b * CDIM * HWDIM + hw;
    float s0 = 0.f, s1 = 0.f, s2 = 0.f, s3 = 0.f;
    #pragma unroll 4
    for (int c = 0; c < CDIM; c += 4) {
        s0 += p[(size_t)(c + 0) * HWDIM];
        s1 += p[(size_t)(c + 1) * HWDIM];
        s2 += p[(size_t)(c + 2) * HWDIM];
        s3 += p[(size_t)(c + 3) * HWDIM];
    }
    resp[gid] = (s0 + s1) + (s2 + s3);
}

// ---------------- K2: per-window argmax (first occurrence) ----------------
__global__ void argmax_kernel(const float* __restrict__ resp, int* __restrict__ kp) {
    int win = blockIdx.x;                 // b*K + k
    int b = win / KKP, k = win % KKP;
    int bi = k / SADMP, bj = k % SADMP;
    int l = threadIdx.x;                  // 0..63 == loc
    int r = l >> 3, c = l & 7;
    int h = bi * BHW + r, w = bj * BHW + c;
    float v = resp[b * HWDIM + h * WDIM + w];
    int idx = l;
    #pragma unroll
    for (int off = 32; off; off >>= 1) {
        float ov = __shfl_down(v, off);
        int   oi = __shfl_down(idx, off);
        if (ov > v || (ov == v && oi < idx)) { v = ov; idx = oi; }
    }
    if (l == 0) {
        int row = bi * BHW + (idx >> 3);
        int col = bj * BHW + (idx & 7);
        kp[win] = row * WDIM + col;
    }
}

// ---------------- K3: gather + hi/lo convert into MFMA-fragment order + dn ----------------
__global__ void convert_kernel(const float* __restrict__ A, const int* __restrict__ kp,
                               uint4* __restrict__ frag, float* __restrict__ dn) {
    int blk = blockIdx.x;                 // b*16 + mf
    int b = blk >> 4, mf = blk & 15;
    int t = threadIdx.x;                  // 0..255
    int l = t & 63, q0 = t >> 6;
    int ml = l & 15;
    int m  = mf * 16 + ml;
    int cg = (l >> 4) * 8;
    int idx = kp[b * KKP + m];
    const float* Ab = A + (size_t)b * CDIM * HWDIM + idx;
    float sq = 0.f;
    #pragma unroll
    for (int qq = 0; qq < 4; qq++) {
        int q = q0 * 4 + qq;
        unsigned hi[4], lo[4];
        #pragma unroll
        for (int jj = 0; jj < 4; jj++) {
            int c0 = q * 32 + cg + jj * 2;
            float v0 = Ab[(size_t)c0 * HWDIM];
            float v1 = Ab[(size_t)(c0 + 1) * HWDIM];
            sq = fmaf(v0, v0, sq);
            sq = fmaf(v1, v1, sq);
            unsigned short h0 = f2bf(v0), h1 = f2bf(v1);
            unsigned short l0 = f2bf(v0 - bf2f(h0)), l1 = f2bf(v1 - bf2f(h1));
            hi[jj] = (unsigned)h0 | ((unsigned)h1 << 16);
            lo[jj] = (unsigned)l0 | ((unsigned)l1 << 16);
        }
        frag[((size_t)b * 2 + 0) * 16384 + mf * 1024 + q * 64 + l] = make_uint4(hi[0], hi[1], hi[2], hi[3]);
        frag[((size_t)b * 2 + 1) * 16384 + mf * 1024 + q * 64 + l] = make_uint4(lo[0], lo[1], lo[2], lo[3]);
    }
    __shared__ float red[16][17];
    red[ml][(l >> 4) * 4 + q0] = sq;
    __syncthreads();
    if (t < 16) {
        float s = 0.f;
        #pragma unroll
        for (int i = 0; i < 16; i++) s += red[t][i];
        dn[b * KKP + mf * 16 + t] = s;
    }
}

// ---------------- K4: MFMA dist + argmin ----------------
// BM=256, BN=32, BK=64/step, 8 steps, bf16 hi/lo 3-term split.
// Fragment-order LDS (conflict-free), double-buffered, ONE barrier per step,
// fb prefetch issued AFTER the barrier (nothing in flight at barriers).
// acc[2][2]=16 VGPRs keeps us under the 64-VGPR occupancy cliff (m69).
__global__ __launch_bounds__(512, 8) void dist_mfma_kernel(
    const uint4* __restrict__ fragA, const float* __restrict__ fb,
    const float* __restrict__ dn, unsigned long long* __restrict__ minkey)
{
    const int n0 = blockIdx.x * 32;
    const int b  = blockIdx.y;
    const int t  = threadIdx.x;
    const int l  = t & 63;
    const int w  = t >> 6;                // wave 0..7: rows w*32 .. w*32+31

    // [buf:2][term:2][ch:2][nf:2][1024B] = 16 KB
    __shared__ char sb[16384];
    __shared__ float bnp[16][32];
    __shared__ float bnf[32];
    __shared__ float dnl[256];

    if (t < 256) dnl[t] = dn[b * KKP + t];

    f32x4 acc[2][2] = {};                 // [mfl][nf]

    // staging map: thread t stages 4 channels (cg..cg+3) of column n0+ncol
    const int ncol = t & 31;
    const int cg   = (t >> 5) * 4;        // 0..60
    const int wb   = (cg >> 5) * 2048 + (ncol >> 4) * 1024
                   + (((cg & 31) >> 3) * 16 + (ncol & 15)) * 16 + (cg & 4) * 2;
    const float* fbp = fb + (size_t)b * CDIM * HWDIM + (size_t)cg * HWDIM + n0 + ncol;
    float bnacc = 0.f;

    const short8* fA = (const short8*)fragA;
    const size_t aBase = (size_t)b * 32768;   // term0; term1 at +16384 (uint4 units)

    float v[4];
    #pragma unroll
    for (int i = 0; i < 4; i++) v[i] = fbp[(size_t)i * HWDIM];

    for (int s = 0; s < 8; s++) {
        const int cur = s & 1;
        // convert current step's 4 values -> frag-order LDS
        {
            float v0 = v[0], v1 = v[1], v2 = v[2], v3 = v[3];
            bnacc = fmaf(v0, v0, bnacc); bnacc = fmaf(v1, v1, bnacc);
            bnacc = fmaf(v2, v2, bnacc); bnacc = fmaf(v3, v3, bnacc);
            unsigned short h0 = f2bf(v0), h1 = f2bf(v1), h2 = f2bf(v2), h3 = f2bf(v3);
            unsigned short g0 = f2bf(v0 - bf2f(h0)), g1 = f2bf(v1 - bf2f(h1));
            unsigned short g2 = f2bf(v2 - bf2f(h2)), g3 = f2bf(v3 - bf2f(h3));
            unsigned hiw0 = (unsigned)h0 | ((unsigned)h1 << 16);
            unsigned hiw1 = (unsigned)h2 | ((unsigned)h3 << 16);
            unsigned low0 = (unsigned)g0 | ((unsigned)g1 << 16);
            unsigned low1 = (unsigned)g2 | ((unsigned)g3 << 16);
            char* wp = sb + cur * 8192 + wb;
            *(uint2*)(wp)        = make_uint2(hiw0, hiw1);
            *(uint2*)(wp + 4096) = make_uint2(low0, low1);
        }
        __syncthreads();
        // prefetch next step AFTER the barrier: spans the MFMA cluster,
        // consumed by next convert before the next barrier.
        if (s < 7) {
            #pragma unroll
            for (int i = 0; i < 4; i++)
                v[i] = fbp[(size_t)((s + 1) * 64 + i) * HWDIM];
        }
        #pragma unroll
        for (int ch = 0; ch < 2; ch++) {
            const int q = s * 2 + ch;
            short8 ah0 = fA[aBase +         (size_t)(w * 2 + 0) * 1024 + q * 64 + l];
            short8 ah1 = fA[aBase +         (size_t)(w * 2 + 1) * 1024 + q * 64 + l];
            short8 al0 = fA[aBase + 16384 + (size_t)(w * 2 + 0) * 1024 + q * 64 + l];
            short8 al1 = fA[aBase + 16384 + (size_t)(w * 2 + 1) * 1024 + q * 64 + l];
            const char* rp = sb + cur * 8192 + ch * 2048 + l * 16;
            #pragma unroll
            for (int nf = 0; nf < 2; nf++) {
                short8 bh = *(const short8*)(rp + nf * 1024);
                short8 bl = *(const short8*)(rp + nf * 1024 + 4096);
                acc[0][nf] = __builtin_amdgcn_mfma_f32_16x16x32_bf16(ah0, bh, acc[0][nf], 0, 0, 0);
                acc[0][nf] = __builtin_amdgcn_mfma_f32_16x16x32_bf16(ah0, bl, acc[0][nf], 0, 0, 0);
                acc[0][nf] = __builtin_amdgcn_mfma_f32_16x16x32_bf16(al0, bh, acc[0][nf], 0, 0, 0);
                acc[1][nf] = __builtin_amdgcn_mfma_f32_16x16x32_bf16(ah1, bh, acc[1][nf], 0, 0, 0);
                acc[1][nf] = __builtin_amdgcn_mfma_f32_16x16x32_bf16(ah1, bl, acc[1][nf], 0, 0, 0);
                acc[1][nf] = __builtin_amdgcn_mfma_f32_16x16x32_bf16(al1, bh, acc[1][nf], 0, 0, 0);
            }
        }
        __syncthreads();
    }

    // bn reduction: 16 partials per column
    bnp[t >> 5][ncol] = bnacc;
    __syncthreads();
    if (t < 32) {
        float s = 0.f;
        #pragma unroll
        for (int i = 0; i < 16; i++) s += bnp[i][t];
        bnf[t] = s;
    }
    __syncthreads();

    // epilogue: dist = dn - 2*cross + bn, packed argmin, atomicMin
    #pragma unroll
    for (int mfl = 0; mfl < 2; mfl++) {
        #pragma unroll
        for (int r = 0; r < 4; r++) {
            int m = w * 32 + mfl * 16 + (l >> 4) * 4 + r;
            float dnm = dnl[m];
            unsigned long long best = ~0ull;
            #pragma unroll
            for (int nf = 0; nf < 2; nf++) {
                int nloc = nf * 16 + (l & 15);
                float d = dnm - 2.f * acc[mfl][nf][r] + bnf[nloc];
                unsigned long long key = ((unsigned long long)ordf(d) << 32) | (unsigned)(n0 + nloc);
                if (key < best) best = key;
            }
            #pragma unroll
            for (int off = 1; off < 16; off <<= 1) {
                unsigned long long o = __shfl_xor(best, off);
                if (o < best) best = o;
            }
            if ((l & 15) == 0) atomicMin(&minkey[b * KKP + m], best);
        }
    }
}

// ---------------- K5: finalize ----------------
__global__ void finalize_kernel(const unsigned long long* __restrict__ minkey,
                                const int* __restrict__ kp,
                                float* __restrict__ out)
{
    int b = blockIdx.x;
    int k = threadIdx.x;
    unsigned long long key = minkey[b * KKP + k];
    unsigned n   = (unsigned)(key & 0xffffffffu);
    unsigned top = (unsigned)(key >> 32);
    unsigned fbits = (top & 0x80000000u) ? (top ^ 0x80000000u) : ~top;
    out[8 + b * KKP + k] = __uint_as_float(fbits);

    int idxA = kp[b * KKP + k];
    int rowA = idxA >> 7, colA = idxA & 127;
    int rowB = (int)(n >> 7), colB = (int)(n & 127);
    int drow = rowA - rowB, dcol = colA - colB;
    int code = (drow + 256) * 1024 + (dcol + 256);

    __shared__ int codes[KKP];
    __shared__ int keys[KKP];
    codes[k] = code;
    __syncthreads();
    int cnt = 0;
    for (int j = 0; j < KKP; j++) cnt += (codes[j] == code);
    keys[k] = cnt * 256 + (255 - k);
    __syncthreads();
    for (int s = 128; s; s >>= 1) {
        if (k < s) keys[k] = max(keys[k], keys[k + s]);
        __syncthreads();
    }
    if (k == 0) {
        int bestk = 255 - (keys[0] & 255);
        int bc = codes[bestk];
        int dr = bc / 1024 - 256, dc = bc % 1024 - 256;
        out[b * 2 + 0] = (float)dr;
        out[b * 2 + 1] = (float)dc;
    }
}

extern "C" void kernel_launch(void* const* d_in, const int* in_sizes, int n_in,
                              void* d_out, int out_size, void* d_ws, size_t ws_size,
                              hipStream_t stream) {
    const float* A  = (const float*)d_in[0];
    const float* Bf = (const float*)d_in[1];
    float* out = (float*)d_out;
    char* ws = (char*)d_ws;

    float* resp = (float*)ws;                                   // 256 KB
    int*   kp   = (int*)(ws + 262144);                          // 4 KB
    float* dn   = (float*)(ws + 266240);                        // 4 KB
    unsigned long long* minkey = (unsigned long long*)(ws + 270336); // 8 KB
    uint4* frag = (uint4*)(ws + 278528);                        // 2 MB

    hipMemsetAsync(minkey, 0xFF, BDIM * KKP * sizeof(unsigned long long), stream);
    resp_kernel<<<BDIM * HWDIM / 256, 256, 0, stream>>>(A, resp);
    argmax_kernel<<<BDIM * KKP, 64, 0, stream>>>(resp, kp);
    convert_kernel<<<BDIM * 16, 256, 0, stream>>>(A, kp, frag, dn);
    dist_mfma_kernel<<<dim3(512, BDIM), 512, 0, stream>>>(frag, Bf, dn, minkey);
    finalize_kernel<<<BDIM, KKP, 0, stream>>>(minkey, kp, out);
}

// Round 5
// 171.672 us; speedup vs baseline: 1.3758x; 1.3758x over previous
//
#include <hip/hip_runtime.h>
#include <stdint.h>

#define BDIM 4
#define CDIM 512
#define HDIM 128
#define WDIM 128
#define HWDIM (HDIM*WDIM)
#define SADMP 16
#define BHW 8
#define KKP 256

using short8  = __attribute__((ext_vector_type(8))) short;
using f32x16  = __attribute__((ext_vector_type(16))) float;

__device__ __forceinline__ unsigned short f2bf(float f) {
    unsigned u = __float_as_uint(f);
    unsigned r = (u + 0x7fffu + ((u >> 16) & 1u)) >> 16;
    return (unsigned short)r;
}
__device__ __forceinline__ float bf2f(unsigned short h) {
    return __uint_as_float(((unsigned)h) << 16);
}
__device__ __forceinline__ unsigned int ordf(float f) {
    unsigned u = __float_as_uint(f);
    return (u & 0x80000000u) ? ~u : (u | 0x80000000u);
}

// ---------------- K1: resp[b][hw] = sum_c A[b][c][hw] ----------------
__global__ void resp_kernel(const float* __restrict__ A, float* __restrict__ resp) {
    int gid = blockIdx.x * blockDim.x + threadIdx.x;
    int b = gid / HWDIM, hw = gid % HWDIM;
    const float* p = A + (size_t)b * CDIM * HWDIM + hw;
    float s0 = 0.f, s1 = 0.f, s2 = 0.f, s3 = 0.f;
    #pragma unroll 4
    for (int c = 0; c < CDIM; c += 4) {
        s0 += p[(size_t)(c + 0) * HWDIM];
        s1 += p[(size_t)(c + 1) * HWDIM];
        s2 += p[(size_t)(c + 2) * HWDIM];
        s3 += p[(size_t)(c + 3) * HWDIM];
    }
    resp[gid] = (s0 + s1) + (s2 + s3);
}

// ---------------- K2: per-window argmax (first occurrence) ----------------
__global__ void argmax_kernel(const float* __restrict__ resp, int* __restrict__ kp) {
    int win = blockIdx.x;                 // b*K + k
    int b = win / KKP, k = win % KKP;
    int bi = k / SADMP, bj = k % SADMP;
    int l = threadIdx.x;                  // 0..63 == loc
    int r = l >> 3, c = l & 7;
    int h = bi * BHW + r, w = bj * BHW + c;
    float v = resp[b * HWDIM + h * WDIM + w];
    int idx = l;
    #pragma unroll
    for (int off = 32; off; off >>= 1) {
        float ov = __shfl_down(v, off);
        int   oi = __shfl_down(idx, off);
        if (ov > v || (ov == v && oi < idx)) { v = ov; idx = oi; }
    }
    if (l == 0) {
        int row = bi * BHW + (idx >> 3);
        int col = bj * BHW + (idx & 7);
        kp[win] = row * WDIM + col;
    }
}

// ---------------- K3: gather + hi/lo convert into 32x32 MFMA A-operand order + dn ----
// frag layout (uint4 units): b*32768 + term*16384 + (rt*32 + q)*64 + slot
//   lane/slot s holds A[m = rt*32 + (s&31)][k = q*16 + (s>>5)*8 + j], j=0..7
__global__ void convert_kernel(const float* __restrict__ A, const int* __restrict__ kp,
                               uint4* __restrict__ frag, float* __restrict__ dn) {
    int blk = blockIdx.x;                 // b*8 + rt
    int b = blk >> 3, rt = blk & 7;
    int t = threadIdx.x;                  // 0..255
    int ml = t & 31, cgrp = t >> 5;       // row-in-tile, channel group (64 ch each)
    int m = rt * 32 + ml;
    int idx = kp[b * KKP + m];
    const float* Ab = A + (size_t)b * CDIM * HWDIM + idx;
    float sq = 0.f;
    #pragma unroll
    for (int j = 0; j < 8; j++) {         // chunks of 8 channels
        int c0 = cgrp * 64 + j * 8;
        int q = c0 >> 4;                  // k-slice of 16
        int slot = ((j & 1) << 5) + ml;
        unsigned hi[4], lo[4];
        #pragma unroll
        for (int p = 0; p < 4; p++) {
            float v0 = Ab[(size_t)(c0 + 2 * p) * HWDIM];
            float v1 = Ab[(size_t)(c0 + 2 * p + 1) * HWDIM];
            sq = fmaf(v0, v0, sq);
            sq = fmaf(v1, v1, sq);
            unsigned short h0 = f2bf(v0), h1 = f2bf(v1);
            unsigned short g0 = f2bf(v0 - bf2f(h0)), g1 = f2bf(v1 - bf2f(h1));
            hi[p] = (unsigned)h0 | ((unsigned)h1 << 16);
            lo[p] = (unsigned)g0 | ((unsigned)g1 << 16);
        }
        frag[(size_t)b * 32768 +         (rt * 32 + q) * 64 + slot] = make_uint4(hi[0], hi[1], hi[2], hi[3]);
        frag[(size_t)b * 32768 + 16384 + (rt * 32 + q) * 64 + slot] = make_uint4(lo[0], lo[1], lo[2], lo[3]);
    }
    __shared__ float red[32][9];
    red[ml][cgrp] = sq;
    __syncthreads();
    if (t < 32) {
        float ssum = 0.f;
        #pragma unroll
        for (int i = 0; i < 8; i++) ssum += red[t][i];
        dn[b * KKP + rt * 32 + t] = ssum;
    }
}

// ---------------- K4: MFMA dist + argmin (32x32x16, BM=256, BN=64, BK=64/step) ----
// B staged in LDS in exact 32x32 fragment order: 16 fragments x 1KB
// ([term:2][ct:2][ks:4]); lane-contiguous 16B writes and reads (conflict-free).
// r2's schedule: convert+write -> barrier -> prefetch next -> MFMA -> barrier.
__global__ __launch_bounds__(512) void dist_mfma_kernel(
    const uint4* __restrict__ fragA, const float* __restrict__ fb,
    const float* __restrict__ dn, unsigned long long* __restrict__ minkey)
{
    const int n0 = blockIdx.x * 64;
    const int b  = blockIdx.y;
    const int t  = threadIdx.x;
    const int l  = t & 63;
    const int w  = t >> 6;                // wave 0..7 -> row-tile rt = w

    __shared__ char sb[16384];            // [term][ct][ks][1024B]
    __shared__ float bnp[8][64];
    __shared__ float bnf[64];
    __shared__ float dnl[256];

    if (t < 256) dnl[t] = dn[b * KKP + t];

    f32x16 acc0 = {};                     // ct=0 (cols n0+0..31)
    f32x16 acc1 = {};                     // ct=1 (cols n0+32..63)

    // staging: thread t stages channels sw*8..+7 of column n0+scol
    const int scol = t & 63;
    const int sw   = t >> 6;
    const int wbHi = (((scol >> 5) * 4 + (sw >> 1)) << 10) + ((((sw & 1) << 5) + (scol & 31)) << 4);
    const float* fbp = fb + (size_t)b * CDIM * HWDIM + (size_t)(sw * 8) * HWDIM + n0 + scol;
    float bnacc = 0.f;

    const uint4* fAhi = fragA + (size_t)b * 32768 +         (size_t)w * 2048 + l;
    const uint4* fAlo = fragA + (size_t)b * 32768 + 16384 + (size_t)w * 2048 + l;

    float v[8];
    #pragma unroll
    for (int i = 0; i < 8; i++) v[i] = fbp[(size_t)i * HWDIM];

    for (int s = 0; s < 8; s++) {
        // convert current step's 8 channel values -> frag-order LDS
        {
            unsigned hi[4], lo[4];
            #pragma unroll
            for (int j = 0; j < 4; j++) {
                float v0 = v[2 * j], v1 = v[2 * j + 1];
                bnacc = fmaf(v0, v0, bnacc);
                bnacc = fmaf(v1, v1, bnacc);
                unsigned short h0 = f2bf(v0), h1 = f2bf(v1);
                unsigned short g0 = f2bf(v0 - bf2f(h0)), g1 = f2bf(v1 - bf2f(h1));
                hi[j] = (unsigned)h0 | ((unsigned)h1 << 16);
                lo[j] = (unsigned)g0 | ((unsigned)g1 << 16);
            }
            *(uint4*)(sb + wbHi)        = make_uint4(hi[0], hi[1], hi[2], hi[3]);
            *(uint4*)(sb + wbHi + 8192) = make_uint4(lo[0], lo[1], lo[2], lo[3]);
        }
        __syncthreads();
        // prefetch next step's fb values (issue spans the MFMA cluster)
        if (s < 7) {
            #pragma unroll
            for (int i = 0; i < 8; i++)
                v[i] = fbp[(size_t)((s + 1) * 64 + i) * HWDIM];
        }
        #pragma unroll
        for (int ks = 0; ks < 4; ks++) {
            const int q = s * 4 + ks;
            short8 ah = *(const short8*)(fAhi + q * 64);
            short8 al = *(const short8*)(fAlo + q * 64);
            const char* rp = sb + ks * 1024 + l * 16;
            short8 bh0 = *(const short8*)(rp);
            short8 bh1 = *(const short8*)(rp + 4096);
            short8 bl0 = *(const short8*)(rp + 8192);
            short8 bl1 = *(const short8*)(rp + 12288);
            acc0 = __builtin_amdgcn_mfma_f32_32x32x16_bf16(ah, bh0, acc0, 0, 0, 0);
            acc0 = __builtin_amdgcn_mfma_f32_32x32x16_bf16(ah, bl0, acc0, 0, 0, 0);
            acc0 = __builtin_amdgcn_mfma_f32_32x32x16_bf16(al, bh0, acc0, 0, 0, 0);
            acc1 = __builtin_amdgcn_mfma_f32_32x32x16_bf16(ah, bh1, acc1, 0, 0, 0);
            acc1 = __builtin_amdgcn_mfma_f32_32x32x16_bf16(ah, bl1, acc1, 0, 0, 0);
            acc1 = __builtin_amdgcn_mfma_f32_32x32x16_bf16(al, bh1, acc1, 0, 0, 0);
        }
        __syncthreads();
    }

    // bn reduction: 8 partials per column
    bnp[sw][scol] = bnacc;
    __syncthreads();
    if (t < 64) {
        float s = 0.f;
        #pragma unroll
        for (int i = 0; i < 8; i++) s += bnp[i][t];
        bnf[t] = s;
    }
    __syncthreads();

    // epilogue: dist = dn - 2*cross + bn; packed argmin over 32-lane halves
    const int colL = l & 31, hl = l >> 5;
    #pragma unroll
    for (int r = 0; r < 16; r++) {
        int m = w * 32 + (r & 3) + 8 * (r >> 2) + 4 * hl;
        float dnm = dnl[m];
        float d0 = dnm - 2.f * acc0[r] + bnf[colL];
        float d1 = dnm - 2.f * acc1[r] + bnf[32 + colL];
        unsigned long long k0 = ((unsigned long long)ordf(d0) << 32) | (unsigned)(n0 + colL);
        unsigned long long k1 = ((unsigned long long)ordf(d1) << 32) | (unsigned)(n0 + 32 + colL);
        unsigned long long best = k0 < k1 ? k0 : k1;
        #pragma unroll
        for (int off = 1; off < 32; off <<= 1) {
            unsigned long long o = __shfl_xor(best, off);
            if (o < best) best = o;
        }
        if (colL == 0) atomicMin(&minkey[b * KKP + m], best);
    }
}

// ---------------- K5: finalize ----------------
__global__ void finalize_kernel(const unsigned long long* __restrict__ minkey,
                                const int* __restrict__ kp,
                                float* __restrict__ out)
{
    int b = blockIdx.x;
    int k = threadIdx.x;
    unsigned long long key = minkey[b * KKP + k];
    unsigned n   = (unsigned)(key & 0xffffffffu);
    unsigned top = (unsigned)(key >> 32);
    unsigned fbits = (top & 0x80000000u) ? (top ^ 0x80000000u) : ~top;
    out[8 + b * KKP + k] = __uint_as_float(fbits);

    int idxA = kp[b * KKP + k];
    int rowA = idxA >> 7, colA = idxA & 127;
    int rowB = (int)(n >> 7), colB = (int)(n & 127);
    int drow = rowA - rowB, dcol = colA - colB;
    int code = (drow + 256) * 1024 + (dcol + 256);

    __shared__ int codes[KKP];
    __shared__ int keys[KKP];
    codes[k] = code;
    __syncthreads();
    int cnt = 0;
    for (int j = 0; j < KKP; j++) cnt += (codes[j] == code);
    keys[k] = cnt * 256 + (255 - k);
    __syncthreads();
    for (int s = 128; s; s >>= 1) {
        if (k < s) keys[k] = max(keys[k], keys[k + s]);
        __syncthreads();
    }
    if (k == 0) {
        int bestk = 255 - (keys[0] & 255);
        int bc = codes[bestk];
        int dr = bc / 1024 - 256, dc = bc % 1024 - 256;
        out[b * 2 + 0] = (float)dr;
        out[b * 2 + 1] = (float)dc;
    }
}

extern "C" void kernel_launch(void* const* d_in, const int* in_sizes, int n_in,
                              void* d_out, int out_size, void* d_ws, size_t ws_size,
                              hipStream_t stream) {
    const float* A  = (const float*)d_in[0];
    const float* Bf = (const float*)d_in[1];
    float* out = (float*)d_out;
    char* ws = (char*)d_ws;

    float* resp = (float*)ws;                                   // 256 KB
    int*   kp   = (int*)(ws + 262144);                          // 4 KB
    float* dn   = (float*)(ws + 266240);                        // 4 KB
    unsigned long long* minkey = (unsigned long long*)(ws + 270336); // 8 KB
    uint4* frag = (uint4*)(ws + 278528);                        // 2 MB

    hipMemsetAsync(minkey, 0xFF, BDIM * KKP * sizeof(unsigned long long), stream);
    resp_kernel<<<BDIM * HWDIM / 256, 256, 0, stream>>>(A, resp);
    argmax_kernel<<<BDIM * KKP, 64, 0, stream>>>(resp, kp);
    convert_kernel<<<BDIM * 8, 256, 0, stream>>>(A, kp, frag, dn);
    dist_mfma_kernel<<<dim3(256, BDIM), 512, 0, stream>>>(frag, Bf, dn, minkey);
    finalize_kernel<<<BDIM, KKP, 0, stream>>>(minkey, kp, out);
}